// Round 19
// baseline (134.320 us; speedup 1.0000x reference)
//
#include <hip/hip_runtime.h>
#include <math.h>

#define T_SEQ 2048
#define BSZ   2
#define DIM   768
#define NH    12
#define SCALE_L2 0.05205877f   /* log2(e)/sqrt(768) : log2-domain scores */

typedef float f32x4 __attribute__((ext_vector_type(4)));
typedef __bf16 bf16x8 __attribute__((ext_vector_type(8)));
typedef unsigned int uint_t;
typedef unsigned short us16;

static __device__ __forceinline__ f32x4 mfma16(bf16x8 a, bf16x8 b, f32x4 c) {
    return __builtin_amdgcn_mfma_f32_16x16x32_bf16(a, b, c, 0, 0, 0);
}
static __device__ __forceinline__ us16 f2bf(float f) {          // RNE
    uint_t u = __builtin_bit_cast(uint_t, f);
    u += 0x7fff + ((u >> 16) & 1);
    return (us16)(u >> 16);
}
static __device__ __forceinline__ us16 f2bf_up(float f) {       // round-half-up (p >= 0)
    return (us16)((__builtin_bit_cast(uint_t, f) + 0x8000u) >> 16);
}
static __device__ __forceinline__ float bf2f(us16 h) {
    return __builtin_bit_cast(float, (uint_t)h << 16);
}
static __device__ __forceinline__ bf16x8 ld_frag(const us16* p) {
    union { uint4 u; bf16x8 b; } x;
    x.u = *(const uint4*)p;
    return x.b;
}

typedef __attribute__((address_space(1))) const unsigned int guint;
typedef __attribute__((address_space(3))) unsigned int luint;
static __device__ __forceinline__ void glds16(const us16* g, us16* l) {
    __builtin_amdgcn_global_load_lds((guint*)g, (luint*)l, 16, 0, 0);
}

// chunk tables (R16): 40 slots per head, max chunk 8 (i-tile ib, j-tiles [c0,c1))
__constant__ int SLOT_IB[40] = {15,15,15,15, 14,14,14,14, 13,13,13,13, 12,12,12,12,
                                11,11,11, 10,10,10, 9,9,9, 8,8,8,
                                7,7, 6,6, 5,5, 4,4, 3, 2, 1, 0};
__constant__ int SLOT_C0[40] = {0,8,16,24, 0,8,16,24, 0,8,16,24, 0,8,16,24,
                                0,8,16, 0,8,16, 0,8,16, 0,8,16,
                                0,8, 0,8, 0,8, 0,8, 0, 0, 0, 0};
__constant__ int SLOT_C1[40] = {8,16,24,32, 8,16,24,30, 8,16,24,28, 8,16,24,26,
                                8,16,24, 8,16,22, 8,16,20, 8,16,18,
                                8,16, 8,14, 8,12, 8,10, 8, 6, 4, 2};
// LPT dispatch order: slots sorted by chunk size desc (28x 8-tile, then 6s, 4s, 2s)
__constant__ int ORDER[40] = {0,1,2,3,4,5,6,8,9,10,12,13,14,16,17,18,19,20,22,23,
                              25,26,28,29,30,32,34,36,
                              7,21,31,37,  11,24,33,38,  15,27,35,39};
// combine tables, indexed ib-4 (ib = 4..15): first slot, #chunks
__constant__ int CB_BASE[12] = {34,32,30,28, 25,22,19,16, 12,8,4,0};
__constant__ int CB_N[12]    = {2,2,2,2, 3,3,3,3, 4,4,4,4};

// ---------------------------------------------------------------------------
// Fused pre-pass: blocks [0,1024) grid-stride f32->bf16 cast of x and pe;
// blocks [1024,1744) 64x64 transpose+convert of the three weights.
// ---------------------------------------------------------------------------
__global__ __launch_bounds__(256)
void cvt_all(const float* __restrict__ x, us16* __restrict__ xb, int n0,
             const float* __restrict__ pe, us16* __restrict__ peb, int n1,
             const float* __restrict__ w0, us16* __restrict__ o0,
             const float* __restrict__ w1, us16* __restrict__ o1,
             const float* __restrict__ w2, us16* __restrict__ o2) {
    const int bid = blockIdx.x;
    const int tid = threadIdx.x;
    if (bid < 1024) {
        int idx = bid * 256 + tid;
        int stride = 1024 * 256;
        int ntot = n0 + n1;
        for (int i = idx; i < ntot; i += stride) {
            const float4* src;
            ushort4* dst;
            if (i < n0) { src = (const float4*)x + i; dst = (ushort4*)xb + i; }
            else        { src = (const float4*)pe + (i - n0); dst = (ushort4*)peb + (i - n0); }
            float4 f = *src;
            ushort4 o;
            o.x = f2bf(f.x); o.y = f2bf(f.y); o.z = f2bf(f.z); o.w = f2bf(f.w);
            *dst = o;
        }
        return;
    }
    __shared__ us16 Ts[64][72];
    const int wb = bid - 1024;
    const float* in; us16* out; int C, bx, by;
    if (wb < 432)      { in = w0; out = o0; C = 2304; bx = wb % 36;        by = wb / 36; }
    else if (wb < 576) { in = w1; out = o1; C = 768;  bx = (wb - 432) % 12; by = (wb - 432) / 12; }
    else               { in = w2; out = o2; C = 768;  bx = (wb - 576) % 12; by = (wb - 576) / 12; }
    const int R = 768;
    const int c0 = bx * 64, r0 = by * 64;
    {
        const int r = tid >> 2, cq = (tid & 3) * 16;
        const float* src = in + (size_t)(r0 + r) * C + c0 + cq;
        #pragma unroll
        for (int i = 0; i < 4; ++i) {
            float4 f = *(const float4*)(src + i * 4);
            Ts[cq + i * 4 + 0][r] = f2bf(f.x);
            Ts[cq + i * 4 + 1][r] = f2bf(f.y);
            Ts[cq + i * 4 + 2][r] = f2bf(f.z);
            Ts[cq + i * 4 + 3][r] = f2bf(f.w);
        }
    }
    __syncthreads();
    {
        const int oc = tid >> 2, rq = (tid & 3) * 16;
        us16* dst = out + (size_t)(c0 + oc) * R + r0 + rq;
        *(uint4*)dst       = *(uint4*)&Ts[oc][rq];
        *(uint4*)(dst + 8) = *(uint4*)&Ts[oc][rq + 8];
    }
}

// ---------------------------------------------------------------------------
// m97-structure bf16 GEMM core, double-buffered, templated on BM (M-tile).
// ---------------------------------------------------------------------------
template <int BM, typename OutT>
static __device__ __forceinline__
void gemm_body(const us16* __restrict__ A, const us16* __restrict__ Bt,
               OutT* __restrict__ C, int N, int K, int m0, int n0,
               us16* As /*2*BM*32*/, us16* Bs /*2*128*32*/) {
    constexpr int MI   = BM / 32;
    constexpr int ABUF = BM * 32;
    const int tid  = threadIdx.x;
    const int lane = tid & 63;
    const int w    = tid >> 6;
    const int g    = lane >> 4;
    const int lm   = lane & 15;
    const int wm = (w >> 1) * (MI * 16), wn = (w & 1) * 64;

    const int nc0 = (w * 2 + 0) * 64 + lane;
    const int nc1 = (w * 2 + 1) * 64 + lane;
    const us16* bs0 = Bt + (size_t)(n0 + (nc0 >> 2)) * K + (nc0 & 3) * 8;
    const us16* bs1 = Bt + (size_t)(n0 + (nc1 >> 2)) * K + (nc1 & 3) * 8;

    const us16* as0;
    const us16* as1 = nullptr;
    if constexpr (BM == 128) {
        as0 = A + (size_t)(m0 + (nc0 >> 2)) * K + (nc0 & 3) * 8;
        as1 = A + (size_t)(m0 + (nc1 >> 2)) * K + (nc1 & 3) * 8;
    } else {
        const int nca = w * 64 + lane;
        as0 = A + (size_t)(m0 + (nca >> 2)) * K + (nca & 3) * 8;
    }

    f32x4 acc[MI][4];
    #pragma unroll
    for (int i = 0; i < MI; ++i)
        #pragma unroll
        for (int j = 0; j < 4; ++j) acc[i][j] = (f32x4){0.f, 0.f, 0.f, 0.f};

    auto STAGE = [&](int buf) {
        if constexpr (BM == 128) {
            glds16(as0, &As[buf * ABUF + (w * 2 + 0) * 512]);
            glds16(as1, &As[buf * ABUF + (w * 2 + 1) * 512]);
            as0 += 32; as1 += 32;
        } else {
            glds16(as0, &As[buf * ABUF + w * 512]);
            as0 += 32;
        }
        glds16(bs0, &Bs[buf * 4096 + (w * 2 + 0) * 512]);
        glds16(bs1, &Bs[buf * 4096 + (w * 2 + 1) * 512]);
        bs0 += 32; bs1 += 32;
    };
    auto COMPUTE = [&](int buf) {
        bf16x8 af[MI], bfr[4];
        #pragma unroll
        for (int mi = 0; mi < MI; ++mi)
            af[mi]  = ld_frag(&As[buf * ABUF + (wm + mi * 16 + lm) * 32 + g * 8]);
        #pragma unroll
        for (int ni = 0; ni < 4; ++ni)
            bfr[ni] = ld_frag(&Bs[buf * 4096 + (wn + ni * 16 + lm) * 32 + g * 8]);
        #pragma unroll
        for (int mi = 0; mi < MI; ++mi)
            #pragma unroll
            for (int ni = 0; ni < 4; ++ni)
                acc[mi][ni] = mfma16(af[mi], bfr[ni], acc[mi][ni]);
    };

    const int nsteps = K / 32;
    STAGE(0);
    __syncthreads();
    for (int it = 0; it < nsteps / 2; ++it) {
        STAGE(1);
        COMPUTE(0);
        __syncthreads();
        if (it * 2 + 2 < nsteps) STAGE(0);
        COMPUTE(1);
        __syncthreads();
    }

    #pragma unroll
    for (int mi = 0; mi < MI; ++mi) {
        #pragma unroll
        for (int reg = 0; reg < 4; ++reg) {
            int row = m0 + wm + mi * 16 + g * 4 + reg;
            OutT* crow = C + (size_t)row * N + n0 + wn + lm;
            #pragma unroll
            for (int ni = 0; ni < 4; ++ni) {
                float v = acc[mi][ni][reg];
                if constexpr (sizeof(OutT) == 2)
                    *(us16*)&crow[ni * 16] = f2bf(v);
                else
                    crow[ni * 16] = v;
            }
        }
    }
}

// Fused qkv + pos GEMM: blocks [0,576) = xb@Wqkvb -> qkvb (4096x2304),
// blocks [576,672) = peb@Wposb -> posb (2048x768). K=768 both.
__global__ __launch_bounds__(256)
void gemm_dual(const us16* __restrict__ A0, const us16* __restrict__ B0, us16* __restrict__ C0,
               const us16* __restrict__ A1, const us16* __restrict__ B1, us16* __restrict__ C1) {
    __shared__ us16 As[2 * 128 * 32];
    __shared__ us16 Bs[2 * 128 * 32];
    const int bid = blockIdx.x;
    if (bid < 576) {
        gemm_body<128, us16>(A0, B0, C0, 2304, 768, (bid / 18) * 128, (bid % 18) * 128, As, Bs);
    } else {
        const int b = bid - 576;
        gemm_body<128, us16>(A1, B1, C1, 768, 768, (b / 6) * 128, (b % 6) * 128, As, Bs);
    }
}

// Out-GEMM (f32 output): BM=64 tiles -> 384 blocks (TLP for the small GEMM).
__global__ __launch_bounds__(256)
void gemm_out(const us16* __restrict__ A, const us16* __restrict__ Bt,
              float* __restrict__ C) {
    __shared__ us16 As[2 * 64 * 32];
    __shared__ us16 Bs[2 * 128 * 32];
    gemm_body<64, float>(A, Bt, C, 768, 768, (int)blockIdx.y * 64, (int)blockIdx.x * 128, As, Bs);
}

// ---------------------------------------------------------------------------
// Chunked MFMA flash attention — R16 configuration (40-slot max-8 tables,
// LPT mapping, pO stride 36); inner loop byte-identical to verified R8.
// ---------------------------------------------------------------------------
__global__ __launch_bounds__(512, 4)
void attn_mfma(const us16* __restrict__ qkvb, const us16* __restrict__ posb,
               const float* __restrict__ u_bias, const float* __restrict__ v_bias,
               us16* __restrict__ ctx, float* __restrict__ pO, float* __restrict__ pML)
{
    __shared__ us16 Ks[64][72];
    __shared__ us16 Vt[80][72];      // rows 64..79 = 1.0 -> l-column via MFMA
    __shared__ us16 Band[256][72];   // circular, slot = t & 255
    __shared__ us16 Ps[8][16][72];

    const int tid  = threadIdx.x;
    const int lane = tid & 63;
    const int w    = tid >> 6;
    const int g    = lane >> 4;
    const int lm   = lane & 15;

    // LPT mapping: dispatch-order rank -> size-sorted slot; heads interleaved
    const int flat = (int)blockIdx.y * 40 + (int)blockIdx.x;
    const int rank = flat / 24;
    const int y    = flat % 24;
    const int slot = ORDER[rank];

    const int ib = SLOT_IB[slot];
    const int c0 = SLOT_C0[slot], c1 = SLOT_C1[slot];
    const int i0 = ib * 128;
    const int n  = y % NH, b = y / NH;
    const int i_w0 = i0 + w * 16;
    const bool multi = (ib >= 4);

    // --- ones rows for the l-reduction block ---
    for (int idx = tid; idx < 576; idx += 512) {
        int r = idx / 36, c = (idx % 36) * 2;
        *(uint_t*)&Vt[64 + r][c] = 0x3F803F80u;
    }

    // --- Q fragments (bias added, log2-scale folded) ---
    bf16x8 Qu[2], Qv[2];
    {
        const int qi = i_w0 + lm;
        const us16* qrow = qkvb + (size_t)(qi * BSZ + b) * 2304 + n * 64;
        #pragma unroll
        for (int ks = 0; ks < 2; ++ks) {
            const int h0 = ks * 32 + g * 8;
            union { uint4 u; us16 s[8]; } q;
            q.u = *(const uint4*)(qrow + h0);
            union { bf16x8 bv; us16 s[8]; } fu, fv;
            #pragma unroll
            for (int e = 0; e < 8; ++e) {
                float f  = bf2f(q.s[e]);
                fu.s[e] = f2bf((f + u_bias[n * 64 + h0 + e]) * SCALE_L2);
                fv.s[e] = f2bf((f + v_bias[n * 64 + h0 + e]) * SCALE_L2);
            }
            Qu[ks] = fu.bv; Qv[ks] = fv.bv;
        }
    }

    // --- prologue: stage tile c0 ---
    const int jr = tid >> 3, cc = (tid & 7) * 8;
    const int jp = tid & 31, hb = (tid >> 5) * 4;
    {
        const int j0 = c0 * 64;
        *(uint4*)&Ks[jr][cc] =
            *(const uint4*)(qkvb + (size_t)((j0 + jr) * BSZ + b) * 2304 + 768 + n * 64 + cc);
        const us16* v0 = qkvb + (size_t)((j0 + 2 * jp) * BSZ + b) * 2304 + 1536 + n * 64 + hb;
        union { uint2 u; us16 s[4]; } r0, r1;
        r0.u = *(const uint2*)v0;
        r1.u = *(const uint2*)(v0 + 2 * 2304);
        #pragma unroll
        for (int k = 0; k < 4; ++k)
            *(uint_t*)&Vt[hb + k][2 * jp] = (uint_t)r0.s[k] | ((uint_t)r1.s[k] << 16);
        const int t_min0 = T_SEQ - 128 - i0 + j0;
        #pragma unroll
        for (int pass = 0; pass < 3; ++pass) {
            int t = t_min0 + pass * 64 + jr;
            uint4 val = make_uint4(0u, 0u, 0u, 0u);
            if (t < T_SEQ)
                val = *(const uint4*)(posb + (size_t)t * DIM + n * 64 + cc);
            *(uint4*)&Band[t & 255][cc] = val;
        }
    }
    __syncthreads();

    f32x4 Oacc[5];                    // [0..3] = O, [4] = l
    #pragma unroll
    for (int hs = 0; hs < 5; ++hs) Oacc[hs] = (f32x4){0.f, 0.f, 0.f, 0.f};
    float m = -INFINITY;              // group-shared running max (log2 domain)

    const int base_w = 112 - 16 * w;

    uint4 sK, sB;
    uint2 sV0, sV1;

    for (int jt = c0; jt < c1; ++jt) {
        const int j0 = jt * 64;
        const int t_min = T_SEQ - 128 - i0 + j0;
        const bool pf = (jt + 1 < c1);

        if (pf) {
            const int j0n = j0 + 64;
            sK = *(const uint4*)(qkvb + (size_t)((j0n + jr) * BSZ + b) * 2304 + 768 + n * 64 + cc);
            const us16* v0 = qkvb + (size_t)((j0n + 2 * jp) * BSZ + b) * 2304 + 1536 + n * 64 + hb;
            sV0 = *(const uint2*)v0;
            sV1 = *(const uint2*)(v0 + 2 * 2304);
            const int t_new = t_min + 192 + jr;
            sB = make_uint4(0u, 0u, 0u, 0u);
            if (t_new < T_SEQ)
                sB = *(const uint4*)(posb + (size_t)t_new * DIM + n * 64 + cc);
        }

        // --- MFMA cluster: R (rel band) and S (content) ---
        __builtin_amdgcn_s_setprio(1);
        f32x4 R[5];
        {
            const int rb = t_min + base_w + lm;
            #pragma unroll
            for (int gs = 0; gs < 5; ++gs) {
                const int row = (rb + gs * 16) & 255;
                f32x4 a = (f32x4){0.f, 0.f, 0.f, 0.f};
                a = mfma16(Qv[0], ld_frag(&Band[row][g * 8]), a);
                a = mfma16(Qv[1], ld_frag(&Band[row][32 + g * 8]), a);
                R[gs] = a;
            }
        }
        f32x4 S4[4];
        #pragma unroll
        for (int js = 0; js < 4; ++js) {
            f32x4 s4 = (f32x4){0.f, 0.f, 0.f, 0.f};
            s4 = mfma16(Qu[0], ld_frag(&Ks[js * 16 + lm][g * 8]), s4);
            s4 = mfma16(Qu[1], ld_frag(&Ks[js * 16 + lm][32 + g * 8]), s4);
            S4[js] = s4;
        }
        __builtin_amdgcn_s_setprio(0);

        // --- gather rel term; mask only on diagonal tiles (wave-uniform) ---
        float sv[4][4];
        if (j0 + 63 <= i_w0) {
            #pragma unroll
            for (int reg = 0; reg < 4; ++reg) {
                const int r   = g * 4 + reg;
                const int idx = lm + 15 - r;
                const int rot = (lane & 48) | (idx & 15);
                #pragma unroll
                for (int js = 0; js < 4; ++js) {
                    float va = __shfl(R[js][reg], rot);
                    float vb = __shfl(R[js + 1][reg], rot);
                    sv[js][reg] = S4[js][reg] + ((idx & 16) ? vb : va);
                }
            }
        } else {
            #pragma unroll
            for (int reg = 0; reg < 4; ++reg) {
                const int r   = g * 4 + reg;
                const int idx = lm + 15 - r;
                const int rot = (lane & 48) | (idx & 15);
                #pragma unroll
                for (int js = 0; js < 4; ++js) {
                    float va = __shfl(R[js][reg], rot);
                    float vb = __shfl(R[js + 1][reg], rot);
                    float rv = (idx & 16) ? vb : va;
                    int jg = j0 + js * 16 + lm;
                    sv[js][reg] = (jg <= i_w0 + r) ? (S4[js][reg] + rv) : -INFINITY;
                }
            }
        }

        // --- group-shared deferred max ---
        float tm = sv[0][0];
        #pragma unroll
        for (int js = 0; js < 4; ++js)
            #pragma unroll
            for (int reg = 0; reg < 4; ++reg) tm = fmaxf(tm, sv[js][reg]);
        #pragma unroll
        for (int d = 1; d < 16; d <<= 1) tm = fmaxf(tm, __shfl_xor(tm, d));
        if (tm > m + 8.0f) {
            float alpha = __builtin_amdgcn_exp2f(m - tm);
            m = tm;
            #pragma unroll
            for (int hs = 0; hs < 5; ++hs)
                #pragma unroll
                for (int reg = 0; reg < 4; ++reg) Oacc[hs][reg] *= alpha;
        }

        // --- P = exp2(s - m), store bf16 ---
        #pragma unroll
        for (int reg = 0; reg < 4; ++reg) {
            const int r = g * 4 + reg;
            #pragma unroll
            for (int js = 0; js < 4; ++js) {
                float p = __builtin_amdgcn_exp2f(sv[js][reg] - m);
                Ps[w][r][js * 16 + lm] = f2bf_up(p);
            }
        }

        // --- PV (+ l-column via ones rows) ---
        __builtin_amdgcn_s_setprio(1);
        #pragma unroll
        for (int ks = 0; ks < 2; ++ks) {
            bf16x8 Pf = ld_frag(&Ps[w][lm][ks * 32 + g * 8]);
            #pragma unroll
            for (int hs = 0; hs < 5; ++hs) {
                bf16x8 Vf = ld_frag(&Vt[hs * 16 + lm][ks * 32 + g * 8]);
                Oacc[hs] = mfma16(Pf, Vf, Oacc[hs]);
            }
        }
        __builtin_amdgcn_s_setprio(0);

        if (pf) {
            __syncthreads();
            *(uint4*)&Ks[jr][cc] = sK;
            union { uint2 u; us16 s[4]; } r0, r1;
            r0.u = sV0; r1.u = sV1;
            #pragma unroll
            for (int k = 0; k < 4; ++k)
                *(uint_t*)&Vt[hb + k][2 * jp] = (uint_t)r0.s[k] | ((uint_t)r1.s[k] << 16);
            const int t_new = t_min + 192 + jr;
            *(uint4*)&Band[t_new & 255][cc] = sB;
            __syncthreads();
        }
    }

    // --- epilogue ---
    if (multi) {
        const size_t pbase = ((size_t)y * 36 + slot) * 128;
        #pragma unroll
        for (int reg = 0; reg < 4; ++reg) {
            const int r = w * 16 + g * 4 + reg;
            float* orow = pO + (pbase + r) * 64 + lm;
            #pragma unroll
            for (int hs = 0; hs < 4; ++hs) orow[hs * 16] = Oacc[hs][reg];
            if (lm == 0) {
                pML[(pbase + r) * 2 + 0] = m;
                pML[(pbase + r) * 2 + 1] = Oacc[4][reg];
            }
        }
    } else {
        #pragma unroll
        for (int reg = 0; reg < 4; ++reg) {
            const int ig = i_w0 + g * 4 + reg;
            float inv = 1.0f / Oacc[4][reg];
            us16* crow = ctx + (size_t)(ig * BSZ + b) * DIM + n * 64;
            #pragma unroll
            for (int hs = 0; hs < 4; ++hs)
                crow[hs * 16 + lm] = f2bf(Oacc[hs][reg] * inv);
        }
    }
}

// ---------------------------------------------------------------------------
// Combine partial chunks (log2-domain m): O = sum_c 2^(m_c-m*) O_c / sum l.
// ---------------------------------------------------------------------------
__global__ __launch_bounds__(256)
void attn_combine(const float* __restrict__ pO, const float* __restrict__ pML,
                  us16* __restrict__ ctx) {
    const int ib = 4 + blockIdx.x;
    const int y  = blockIdx.y;
    const int n = y % NH, b = y / NH;
    const int base = CB_BASE[blockIdx.x], nc = CB_N[blockIdx.x];
    const int tid = threadIdx.x;
    const int r = tid >> 1, half = (tid & 1) * 32;

    float mc[4], lc[4], sc[4];
    float mstar = -INFINITY;
    #pragma unroll
    for (int c = 0; c < 4; ++c) {
        mc[c] = -INFINITY; lc[c] = 0.f;
        if (c < nc) {
            const float* ml = pML + ((size_t)(y * 36 + base + c) * 128 + r) * 2;
            mc[c] = ml[0]; lc[c] = ml[1];
        }
        mstar = fmaxf(mstar, mc[c]);
    }
    float lstar = 0.f;
    #pragma unroll
    for (int c = 0; c < 4; ++c) {
        sc[c] = (c < nc) ? __builtin_amdgcn_exp2f(mc[c] - mstar) : 0.f;
        lstar += sc[c] * lc[c];
    }
    const float inv = 1.0f / lstar;

    f32x4 acc[8];
    #pragma unroll
    for (int k = 0; k < 8; ++k) acc[k] = (f32x4){0.f, 0.f, 0.f, 0.f};
    #pragma unroll
    for (int c = 0; c < 4; ++c) {
        if (c < nc) {
            const f32x4* src = (const f32x4*)(pO + ((size_t)(y * 36 + base + c) * 128 + r) * 64 + half);
            float s = sc[c];
            #pragma unroll
            for (int k = 0; k < 8; ++k) acc[k] += src[k] * s;
        }
    }
    const int ig = ib * 128 + r;
    us16* crow = ctx + (size_t)(ig * BSZ + b) * DIM + n * 64 + half;
    #pragma unroll
    for (int k = 0; k < 8; ++k) {
        us16 q[4];
        #pragma unroll
        for (int e = 0; e < 4; ++e) q[e] = f2bf(acc[k][e] * inv);
        *(uint2*)&crow[k * 4] = *(uint2*)q;
    }
}

// ---------------------------------------------------------------------------
extern "C" void kernel_launch(void* const* d_in, const int* in_sizes, int n_in,
                              void* d_out, int out_size, void* d_ws, size_t ws_size,
                              hipStream_t stream) {
    const float* x      = (const float*)d_in[0];
    const float* pe     = (const float*)d_in[1];
    const float* u_bias = (const float*)d_in[2];
    const float* v_bias = (const float*)d_in[3];
    const float* W_qkv  = (const float*)d_in[4];
    const float* W_pos  = (const float*)d_in[5];
    const float* W_out  = (const float*)d_in[6];
    float* out = (float*)d_out;

    char* ws = (char*)d_ws;
    us16*  qkvb  = (us16*)(ws);                 // [4096,2304]  18,874,368 B
    us16*  posb  = (us16*)(ws + 18874368);      // [2048, 768]   3,145,728
    us16*  ctxb  = (us16*)(ws + 22020096);      // [4096, 768]   6,291,456
    us16*  Woutb = (us16*)(ws + 28311552);      // [768][768]^T  1,179,648 (survives attn)
    float* pML   = (float*)(ws + 29491200);     // [24][36][128][2]    884,736
    float* pO    = (float*)(ws + 30375936);     // [24][36][128][64] 28,311,552
    // cvt buffers alias the pO region (dead until attn runs):
    us16*  xb    = (us16*)(ws + 30375936);      // [4096, 768]   6,291,456
    us16*  peb   = (us16*)(ws + 36667392);      // [2048, 768]   3,145,728
    us16*  Wqkvb = (us16*)(ws + 39813120);      // [2304][768]^T 3,538,944
    us16*  Wposb = (us16*)(ws + 43352064);      // [768][768]^T  1,179,648

    dim3 blk(256);
    cvt_all<<<1744, blk, 0, stream>>>(x, xb, 4096 * 768 / 4, pe, peb, 2048 * 768 / 4,
                                      W_qkv, Wqkvb, W_pos, Wposb, W_out, Woutb);
    gemm_dual<<<672, blk, 0, stream>>>(xb, Wqkvb, qkvb, peb, Wposb, posb);
    attn_mfma<<<dim3(40, 24), dim3(512), 0, stream>>>(qkvb, posb, u_bias, v_bias, ctxb, pO, pML);
    attn_combine<<<dim3(12, 24), blk, 0, stream>>>(pO, pML, ctxb);
    gemm_out<<<dim3(768 / 128, 4096 / 64), blk, 0, stream>>>(ctxb, Woutb, out);
}

// Round 20
// 133.985 us; speedup vs baseline: 1.0025x; 1.0025x over previous
//
#include <hip/hip_runtime.h>
#include <math.h>

#define T_SEQ 2048
#define BSZ   2
#define DIM   768
#define NH    12
#define SCALE_L2 0.05205877f   /* log2(e)/sqrt(768) : log2-domain scores */

typedef float f32x4 __attribute__((ext_vector_type(4)));
typedef __bf16 bf16x8 __attribute__((ext_vector_type(8)));
typedef unsigned int uint_t;
typedef unsigned short us16;

static __device__ __forceinline__ f32x4 mfma16(bf16x8 a, bf16x8 b, f32x4 c) {
    return __builtin_amdgcn_mfma_f32_16x16x32_bf16(a, b, c, 0, 0, 0);
}
static __device__ __forceinline__ us16 f2bf(float f) {          // RNE
    uint_t u = __builtin_bit_cast(uint_t, f);
    u += 0x7fff + ((u >> 16) & 1);
    return (us16)(u >> 16);
}
static __device__ __forceinline__ us16 f2bf_up(float f) {       // round-half-up (p >= 0)
    return (us16)((__builtin_bit_cast(uint_t, f) + 0x8000u) >> 16);
}
static __device__ __forceinline__ float bf2f(us16 h) {
    return __builtin_bit_cast(float, (uint_t)h << 16);
}
static __device__ __forceinline__ bf16x8 ld_frag(const us16* p) {
    union { uint4 u; bf16x8 b; } x;
    x.u = *(const uint4*)p;
    return x.b;
}

typedef __attribute__((address_space(1))) const unsigned int guint;
typedef __attribute__((address_space(3))) unsigned int luint;
static __device__ __forceinline__ void glds16(const us16* g, us16* l) {
    __builtin_amdgcn_global_load_lds((guint*)g, (luint*)l, 16, 0, 0);
}

// chunk tables: 30 slots per head, (i-tile ib, j-tiles [c0,c1)).
__constant__ int SLOT_IB[30] = {15,15,15, 14,14,14, 13,13, 12,12, 11,11,
                                10,10, 9,9, 8,8, 7,7, 6,6, 5, 4, 3,3, 2,2, 1, 0};
__constant__ int SLOT_C0[30] = {0,11,22, 0,10,20, 0,14, 0,13, 0,12,
                                0,11, 0,10, 0,14, 0,14, 0,12, 0, 0, 0,4, 0,3, 0, 0};
__constant__ int SLOT_C1[30] = {11,22,32, 10,20,30, 14,28, 13,26, 12,24,
                                11,22, 10,20, 14,18, 14,16, 12,14, 12, 10, 4,8, 3,6, 4, 2};
// LPT dispatch order: 21 bigs desc (14,13,12,11,10), then smalls desc (4,3,2)
__constant__ int ORDER[30] = {6,7,16,18, 8,9, 10,11,20,22, 0,1,12,13,
                              2,3,4,5,14,15,23,
                              17,24,25,28, 26,27, 19,21,29};
// combine tables: column bx -> (ib, first slot, #chunks); multi i-tiles only
__constant__ int CB_IB[12]   = {2,3,6,7,8,9,10,11,12,13,14,15};
__constant__ int CB_BASE[12] = {26,24,20,18,16,14,12,10,8,6,3,0};
__constant__ int CB_N[12]    = {2,2,2,2,2,2,2,2,2,2,3,3};

// ---------------------------------------------------------------------------
// Fused pre-pass: blocks [0,1024) grid-stride f32->bf16 cast of x and pe;
// blocks [1024,1744) 64x64 transpose+convert of the three weights.
// ---------------------------------------------------------------------------
__global__ __launch_bounds__(256)
void cvt_all(const float* __restrict__ x, us16* __restrict__ xb, int n0,
             const float* __restrict__ pe, us16* __restrict__ peb, int n1,
             const float* __restrict__ w0, us16* __restrict__ o0,
             const float* __restrict__ w1, us16* __restrict__ o1,
             const float* __restrict__ w2, us16* __restrict__ o2) {
    const int bid = blockIdx.x;
    const int tid = threadIdx.x;
    if (bid < 1024) {
        int idx = bid * 256 + tid;
        int stride = 1024 * 256;
        int ntot = n0 + n1;
        for (int i = idx; i < ntot; i += stride) {
            const float4* src;
            ushort4* dst;
            if (i < n0) { src = (const float4*)x + i; dst = (ushort4*)xb + i; }
            else        { src = (const float4*)pe + (i - n0); dst = (ushort4*)peb + (i - n0); }
            float4 f = *src;
            ushort4 o;
            o.x = f2bf(f.x); o.y = f2bf(f.y); o.z = f2bf(f.z); o.w = f2bf(f.w);
            *dst = o;
        }
        return;
    }
    __shared__ us16 Ts[64][72];
    const int wb = bid - 1024;
    const float* in; us16* out; int C, bx, by;
    if (wb < 432)      { in = w0; out = o0; C = 2304; bx = wb % 36;        by = wb / 36; }
    else if (wb < 576) { in = w1; out = o1; C = 768;  bx = (wb - 432) % 12; by = (wb - 432) / 12; }
    else               { in = w2; out = o2; C = 768;  bx = (wb - 576) % 12; by = (wb - 576) / 12; }
    const int R = 768;
    const int c0 = bx * 64, r0 = by * 64;
    {
        const int r = tid >> 2, cq = (tid & 3) * 16;
        const float* src = in + (size_t)(r0 + r) * C + c0 + cq;
        #pragma unroll
        for (int i = 0; i < 4; ++i) {
            float4 f = *(const float4*)(src + i * 4);
            Ts[cq + i * 4 + 0][r] = f2bf(f.x);
            Ts[cq + i * 4 + 1][r] = f2bf(f.y);
            Ts[cq + i * 4 + 2][r] = f2bf(f.z);
            Ts[cq + i * 4 + 3][r] = f2bf(f.w);
        }
    }
    __syncthreads();
    {
        const int oc = tid >> 2, rq = (tid & 3) * 16;
        us16* dst = out + (size_t)(c0 + oc) * R + r0 + rq;
        *(uint4*)dst       = *(uint4*)&Ts[oc][rq];
        *(uint4*)(dst + 8) = *(uint4*)&Ts[oc][rq + 8];
    }
}

// ---------------------------------------------------------------------------
// m97-structure bf16 GEMM core, double-buffered, templated on BM (M-tile).
// BM=128: 4 waves x (64x64), 2 A-glds/thread. BM=64: 4 waves x (32x64).
// ---------------------------------------------------------------------------
template <int BM, typename OutT>
static __device__ __forceinline__
void gemm_body(const us16* __restrict__ A, const us16* __restrict__ Bt,
               OutT* __restrict__ C, int N, int K, int m0, int n0,
               us16* As /*2*BM*32*/, us16* Bs /*2*128*32*/) {
    constexpr int MI   = BM / 32;        // 16-row frags per wave
    constexpr int ABUF = BM * 32;        // us16 per A buffer
    const int tid  = threadIdx.x;
    const int lane = tid & 63;
    const int w    = tid >> 6;
    const int g    = lane >> 4;
    const int lm   = lane & 15;
    const int wm = (w >> 1) * (MI * 16), wn = (w & 1) * 64;

    const int nc0 = (w * 2 + 0) * 64 + lane;
    const int nc1 = (w * 2 + 1) * 64 + lane;
    const us16* bs0 = Bt + (size_t)(n0 + (nc0 >> 2)) * K + (nc0 & 3) * 8;
    const us16* bs1 = Bt + (size_t)(n0 + (nc1 >> 2)) * K + (nc1 & 3) * 8;

    const us16* as0;
    const us16* as1 = nullptr;
    if constexpr (BM == 128) {
        as0 = A + (size_t)(m0 + (nc0 >> 2)) * K + (nc0 & 3) * 8;
        as1 = A + (size_t)(m0 + (nc1 >> 2)) * K + (nc1 & 3) * 8;
    } else {
        const int nca = w * 64 + lane;   // 256 chunks cover 64 rows x 32 k
        as0 = A + (size_t)(m0 + (nca >> 2)) * K + (nca & 3) * 8;
    }

    f32x4 acc[MI][4];
    #pragma unroll
    for (int i = 0; i < MI; ++i)
        #pragma unroll
        for (int j = 0; j < 4; ++j) acc[i][j] = (f32x4){0.f, 0.f, 0.f, 0.f};

    auto STAGE = [&](int buf) {
        if constexpr (BM == 128) {
            glds16(as0, &As[buf * ABUF + (w * 2 + 0) * 512]);
            glds16(as1, &As[buf * ABUF + (w * 2 + 1) * 512]);
            as0 += 32; as1 += 32;
        } else {
            glds16(as0, &As[buf * ABUF + w * 512]);
            as0 += 32;
        }
        glds16(bs0, &Bs[buf * 4096 + (w * 2 + 0) * 512]);
        glds16(bs1, &Bs[buf * 4096 + (w * 2 + 1) * 512]);
        bs0 += 32; bs1 += 32;
    };
    auto COMPUTE = [&](int buf) {
        bf16x8 af[MI], bfr[4];
        #pragma unroll
        for (int mi = 0; mi < MI; ++mi)
            af[mi]  = ld_frag(&As[buf * ABUF + (wm + mi * 16 + lm) * 32 + g * 8]);
        #pragma unroll
        for (int ni = 0; ni < 4; ++ni)
            bfr[ni] = ld_frag(&Bs[buf * 4096 + (wn + ni * 16 + lm) * 32 + g * 8]);
        #pragma unroll
        for (int mi = 0; mi < MI; ++mi)
            #pragma unroll
            for (int ni = 0; ni < 4; ++ni)
                acc[mi][ni] = mfma16(af[mi], bfr[ni], acc[mi][ni]);
    };

    const int nsteps = K / 32;
    STAGE(0);
    __syncthreads();
    for (int it = 0; it < nsteps / 2; ++it) {
        STAGE(1);
        COMPUTE(0);
        __syncthreads();
        if (it * 2 + 2 < nsteps) STAGE(0);
        COMPUTE(1);
        __syncthreads();
    }

    #pragma unroll
    for (int mi = 0; mi < MI; ++mi) {
        #pragma unroll
        for (int reg = 0; reg < 4; ++reg) {
            int row = m0 + wm + mi * 16 + g * 4 + reg;
            OutT* crow = C + (size_t)row * N + n0 + wn + lm;
            #pragma unroll
            for (int ni = 0; ni < 4; ++ni) {
                float v = acc[mi][ni][reg];
                if constexpr (sizeof(OutT) == 2)
                    *(us16*)&crow[ni * 16] = f2bf(v);
                else
                    crow[ni * 16] = v;
            }
        }
    }
}

// Fused qkv + pos GEMM: blocks [0,576) = xb@Wqkvb -> qkvb (4096x2304),
// blocks [576,672) = peb@Wposb -> posb (2048x768). K=768 both.
__global__ __launch_bounds__(256)
void gemm_dual(const us16* __restrict__ A0, const us16* __restrict__ B0, us16* __restrict__ C0,
               const us16* __restrict__ A1, const us16* __restrict__ B1, us16* __restrict__ C1) {
    __shared__ us16 As[2 * 128 * 32];
    __shared__ us16 Bs[2 * 128 * 32];
    const int bid = blockIdx.x;
    if (bid < 576) {
        gemm_body<128, us16>(A0, B0, C0, 2304, 768, (bid / 18) * 128, (bid % 18) * 128, As, Bs);
    } else {
        const int b = bid - 576;
        gemm_body<128, us16>(A1, B1, C1, 768, 768, (b / 6) * 128, (b % 6) * 128, As, Bs);
    }
}

// Out-GEMM (f32 output): BM=64 tiles -> 384 blocks (TLP for the small GEMM).
__global__ __launch_bounds__(256)
void gemm_out(const us16* __restrict__ A, const us16* __restrict__ Bt,
              float* __restrict__ C) {
    __shared__ us16 As[2 * 64 * 32];
    __shared__ us16 Bs[2 * 128 * 32];
    gemm_body<64, float>(A, Bt, C, 768, 768, (int)blockIdx.y * 64, (int)blockIdx.x * 128, As, Bs);
}

// ---------------------------------------------------------------------------
// Chunked MFMA flash attention — verified R8 inner loop; 30-slot LPT tables.
// ---------------------------------------------------------------------------
__global__ __launch_bounds__(512, 4)
void attn_mfma(const us16* __restrict__ qkvb, const us16* __restrict__ posb,
               const float* __restrict__ u_bias, const float* __restrict__ v_bias,
               us16* __restrict__ ctx, float* __restrict__ pO, float* __restrict__ pML)
{
    __shared__ us16 Ks[64][72];
    __shared__ us16 Vt[80][72];      // rows 64..79 = 1.0 -> l-column via MFMA
    __shared__ us16 Band[256][72];   // circular, slot = t & 255
    __shared__ us16 Ps[8][16][72];

    const int tid  = threadIdx.x;
    const int lane = tid & 63;
    const int w    = tid >> 6;
    const int g    = lane >> 4;
    const int lm   = lane & 15;

    // LPT mapping: dispatch-order rank -> size-sorted slot; heads interleaved
    const int flat = (int)blockIdx.y * 30 + (int)blockIdx.x;
    const int rank = flat / 24;
    const int y    = flat % 24;
    const int slot = ORDER[rank];

    const int ib = SLOT_IB[slot];
    const int c0 = SLOT_C0[slot], c1 = SLOT_C1[slot];
    const int i0 = ib * 128;
    const int n  = y % NH, b = y / NH;
    const int i_w0 = i0 + w * 16;
    const bool multi = !(ib == 0 || ib == 1 || ib == 4 || ib == 5);

    // --- ones rows for the l-reduction block ---
    for (int idx = tid; idx < 576; idx += 512) {
        int r = idx / 36, c = (idx % 36) * 2;
        *(uint_t*)&Vt[64 + r][c] = 0x3F803F80u;
    }

    // --- Q fragments (bias added, log2-scale folded) ---
    bf16x8 Qu[2], Qv[2];
    {
        const int qi = i_w0 + lm;
        const us16* qrow = qkvb + (size_t)(qi * BSZ + b) * 2304 + n * 64;
        #pragma unroll
        for (int ks = 0; ks < 2; ++ks) {
            const int h0 = ks * 32 + g * 8;
            union { uint4 u; us16 s[8]; } q;
            q.u = *(const uint4*)(qrow + h0);
            union { bf16x8 bv; us16 s[8]; } fu, fv;
            #pragma unroll
            for (int e = 0; e < 8; ++e) {
                float f  = bf2f(q.s[e]);
                fu.s[e] = f2bf((f + u_bias[n * 64 + h0 + e]) * SCALE_L2);
                fv.s[e] = f2bf((f + v_bias[n * 64 + h0 + e]) * SCALE_L2);
            }
            Qu[ks] = fu.bv; Qv[ks] = fv.bv;
        }
    }

    // --- prologue: stage tile c0 ---
    const int jr = tid >> 3, cc = (tid & 7) * 8;
    const int jp = tid & 31, hb = (tid >> 5) * 4;
    {
        const int j0 = c0 * 64;
        *(uint4*)&Ks[jr][cc] =
            *(const uint4*)(qkvb + (size_t)((j0 + jr) * BSZ + b) * 2304 + 768 + n * 64 + cc);
        const us16* v0 = qkvb + (size_t)((j0 + 2 * jp) * BSZ + b) * 2304 + 1536 + n * 64 + hb;
        union { uint2 u; us16 s[4]; } r0, r1;
        r0.u = *(const uint2*)v0;
        r1.u = *(const uint2*)(v0 + 2 * 2304);
        #pragma unroll
        for (int k = 0; k < 4; ++k)
            *(uint_t*)&Vt[hb + k][2 * jp] = (uint_t)r0.s[k] | ((uint_t)r1.s[k] << 16);
        const int t_min0 = T_SEQ - 128 - i0 + j0;
        #pragma unroll
        for (int pass = 0; pass < 3; ++pass) {
            int t = t_min0 + pass * 64 + jr;
            uint4 val = make_uint4(0u, 0u, 0u, 0u);
            if (t < T_SEQ)
                val = *(const uint4*)(posb + (size_t)t * DIM + n * 64 + cc);
            *(uint4*)&Band[t & 255][cc] = val;
        }
    }
    __syncthreads();

    f32x4 Oacc[5];                    // [0..3] = O, [4] = l
    #pragma unroll
    for (int hs = 0; hs < 5; ++hs) Oacc[hs] = (f32x4){0.f, 0.f, 0.f, 0.f};
    float m = -INFINITY;              // group-shared running max (log2 domain)

    const int base_w = 112 - 16 * w;

    uint4 sK, sB;
    uint2 sV0, sV1;

    for (int jt = c0; jt < c1; ++jt) {
        const int j0 = jt * 64;
        const int t_min = T_SEQ - 128 - i0 + j0;
        const bool pf = (jt + 1 < c1);

        if (pf) {
            const int j0n = j0 + 64;
            sK = *(const uint4*)(qkvb + (size_t)((j0n + jr) * BSZ + b) * 2304 + 768 + n * 64 + cc);
            const us16* v0 = qkvb + (size_t)((j0n + 2 * jp) * BSZ + b) * 2304 + 1536 + n * 64 + hb;
            sV0 = *(const uint2*)v0;
            sV1 = *(const uint2*)(v0 + 2 * 2304);
            const int t_new = t_min + 192 + jr;
            sB = make_uint4(0u, 0u, 0u, 0u);
            if (t_new < T_SEQ)
                sB = *(const uint4*)(posb + (size_t)t_new * DIM + n * 64 + cc);
        }

        // --- MFMA cluster: R (rel band) and S (content) ---
        __builtin_amdgcn_s_setprio(1);
        f32x4 R[5];
        {
            const int rb = t_min + base_w + lm;
            #pragma unroll
            for (int gs = 0; gs < 5; ++gs) {
                const int row = (rb + gs * 16) & 255;
                f32x4 a = (f32x4){0.f, 0.f, 0.f, 0.f};
                a = mfma16(Qv[0], ld_frag(&Band[row][g * 8]), a);
                a = mfma16(Qv[1], ld_frag(&Band[row][32 + g * 8]), a);
                R[gs] = a;
            }
        }
        f32x4 S4[4];
        #pragma unroll
        for (int js = 0; js < 4; ++js) {
            f32x4 s4 = (f32x4){0.f, 0.f, 0.f, 0.f};
            s4 = mfma16(Qu[0], ld_frag(&Ks[js * 16 + lm][g * 8]), s4);
            s4 = mfma16(Qu[1], ld_frag(&Ks[js * 16 + lm][32 + g * 8]), s4);
            S4[js] = s4;
        }
        __builtin_amdgcn_s_setprio(0);

        // --- gather rel term; mask only on diagonal tiles (wave-uniform) ---
        float sv[4][4];
        if (j0 + 63 <= i_w0) {
            #pragma unroll
            for (int reg = 0; reg < 4; ++reg) {
                const int r   = g * 4 + reg;
                const int idx = lm + 15 - r;
                const int rot = (lane & 48) | (idx & 15);
                #pragma unroll
                for (int js = 0; js < 4; ++js) {
                    float va = __shfl(R[js][reg], rot);
                    float vb = __shfl(R[js + 1][reg], rot);
                    sv[js][reg] = S4[js][reg] + ((idx & 16) ? vb : va);
                }
            }
        } else {
            #pragma unroll
            for (int reg = 0; reg < 4; ++reg) {
                const int r   = g * 4 + reg;
                const int idx = lm + 15 - r;
                const int rot = (lane & 48) | (idx & 15);
                #pragma unroll
                for (int js = 0; js < 4; ++js) {
                    float va = __shfl(R[js][reg], rot);
                    float vb = __shfl(R[js + 1][reg], rot);
                    float rv = (idx & 16) ? vb : va;
                    int jg = j0 + js * 16 + lm;
                    sv[js][reg] = (jg <= i_w0 + r) ? (S4[js][reg] + rv) : -INFINITY;
                }
            }
        }

        // --- group-shared deferred max ---
        float tm = sv[0][0];
        #pragma unroll
        for (int js = 0; js < 4; ++js)
            #pragma unroll
            for (int reg = 0; reg < 4; ++reg) tm = fmaxf(tm, sv[js][reg]);
        #pragma unroll
        for (int d = 1; d < 16; d <<= 1) tm = fmaxf(tm, __shfl_xor(tm, d));
        if (tm > m + 8.0f) {
            float alpha = __builtin_amdgcn_exp2f(m - tm);
            m = tm;
            #pragma unroll
            for (int hs = 0; hs < 5; ++hs)
                #pragma unroll
                for (int reg = 0; reg < 4; ++reg) Oacc[hs][reg] *= alpha;
        }

        // --- P = exp2(s - m), store bf16 ---
        #pragma unroll
        for (int reg = 0; reg < 4; ++reg) {
            const int r = g * 4 + reg;
            #pragma unroll
            for (int js = 0; js < 4; ++js) {
                float p = __builtin_amdgcn_exp2f(sv[js][reg] - m);
                Ps[w][r][js * 16 + lm] = f2bf_up(p);
            }
        }

        // --- PV (+ l-column via ones rows) ---
        __builtin_amdgcn_s_setprio(1);
        #pragma unroll
        for (int ks = 0; ks < 2; ++ks) {
            bf16x8 Pf = ld_frag(&Ps[w][lm][ks * 32 + g * 8]);
            #pragma unroll
            for (int hs = 0; hs < 5; ++hs) {
                bf16x8 Vf = ld_frag(&Vt[hs * 16 + lm][ks * 32 + g * 8]);
                Oacc[hs] = mfma16(Pf, Vf, Oacc[hs]);
            }
        }
        __builtin_amdgcn_s_setprio(0);

        if (pf) {
            __syncthreads();
            *(uint4*)&Ks[jr][cc] = sK;
            union { uint2 u; us16 s[4]; } r0, r1;
            r0.u = sV0; r1.u = sV1;
            #pragma unroll
            for (int k = 0; k < 4; ++k)
                *(uint_t*)&Vt[hb + k][2 * jp] = (uint_t)r0.s[k] | ((uint_t)r1.s[k] << 16);
            const int t_new = t_min + 192 + jr;
            *(uint4*)&Band[t_new & 255][cc] = sB;
            __syncthreads();
        }
    }

    // --- epilogue ---
    if (multi) {
        const size_t pbase = ((size_t)y * 30 + slot) * 128;
        #pragma unroll
        for (int reg = 0; reg < 4; ++reg) {
            const int r = w * 16 + g * 4 + reg;
            float* orow = pO + (pbase + r) * 64 + lm;
            #pragma unroll
            for (int hs = 0; hs < 4; ++hs) orow[hs * 16] = Oacc[hs][reg];
            if (lm == 0) {
                pML[(pbase + r) * 2 + 0] = m;
                pML[(pbase + r) * 2 + 1] = Oacc[4][reg];
            }
        }
    } else {
        #pragma unroll
        for (int reg = 0; reg < 4; ++reg) {
            const int ig = i_w0 + g * 4 + reg;
            float inv = 1.0f / Oacc[4][reg];
            us16* crow = ctx + (size_t)(ig * BSZ + b) * DIM + n * 64;
            #pragma unroll
            for (int hs = 0; hs < 4; ++hs)
                crow[hs * 16 + lm] = f2bf(Oacc[hs][reg] * inv);
        }
    }
}

// ---------------------------------------------------------------------------
// Combine partial chunks (log2-domain m): O = sum_c 2^(m_c-m*) O_c / sum l.
// ---------------------------------------------------------------------------
__global__ __launch_bounds__(256)
void attn_combine(const float* __restrict__ pO, const float* __restrict__ pML,
                  us16* __restrict__ ctx) {
    const int ib = CB_IB[blockIdx.x];
    const int y  = blockIdx.y;
    const int n = y % NH, b = y / NH;
    const int base = CB_BASE[blockIdx.x], nc = CB_N[blockIdx.x];
    const int tid = threadIdx.x;
    const int r = tid >> 1, half = (tid & 1) * 32;

    float mc[4], lc[4], sc[4];
    float mstar = -INFINITY;
    #pragma unroll
    for (int c = 0; c < 4; ++c) {
        mc[c] = -INFINITY; lc[c] = 0.f;
        if (c < nc) {
            const float* ml = pML + ((size_t)(y * 30 + base + c) * 128 + r) * 2;
            mc[c] = ml[0]; lc[c] = ml[1];
        }
        mstar = fmaxf(mstar, mc[c]);
    }
    float lstar = 0.f;
    #pragma unroll
    for (int c = 0; c < 4; ++c) {
        sc[c] = (c < nc) ? __builtin_amdgcn_exp2f(mc[c] - mstar) : 0.f;
        lstar += sc[c] * lc[c];
    }
    const float inv = 1.0f / lstar;

    f32x4 acc[8];
    #pragma unroll
    for (int k = 0; k < 8; ++k) acc[k] = (f32x4){0.f, 0.f, 0.f, 0.f};
    #pragma unroll
    for (int c = 0; c < 4; ++c) {
        if (c < nc) {
            const f32x4* src = (const f32x4*)(pO + ((size_t)(y * 30 + base + c) * 128 + r) * 64 + half);
            float s = sc[c];
            #pragma unroll
            for (int k = 0; k < 8; ++k) acc[k] += src[k] * s;
        }
    }
    const int ig = ib * 128 + r;
    us16* crow = ctx + (size_t)(ig * BSZ + b) * DIM + n * 64 + half;
    #pragma unroll
    for (int k = 0; k < 8; ++k) {
        us16 q[4];
        #pragma unroll
        for (int e = 0; e < 4; ++e) q[e] = f2bf(acc[k][e] * inv);
        *(uint2*)&crow[k * 4] = *(uint2*)q;
    }
}

// ---------------------------------------------------------------------------
extern "C" void kernel_launch(void* const* d_in, const int* in_sizes, int n_in,
                              void* d_out, int out_size, void* d_ws, size_t ws_size,
                              hipStream_t stream) {
    const float* x      = (const float*)d_in[0];
    const float* pe     = (const float*)d_in[1];
    const float* u_bias = (const float*)d_in[2];
    const float* v_bias = (const float*)d_in[3];
    const float* W_qkv  = (const float*)d_in[4];
    const float* W_pos  = (const float*)d_in[5];
    const float* W_out  = (const float*)d_in[6];
    float* out = (float*)d_out;

    char* ws = (char*)d_ws;
    us16*  qkvb  = (us16*)(ws);                 // [4096,2304]  18,874,368 B
    us16*  posb  = (us16*)(ws + 18874368);      // [2048, 768]   3,145,728
    us16*  ctxb  = (us16*)(ws + 22020096);      // [4096, 768]   6,291,456
    us16*  Woutb = (us16*)(ws + 28311552);      // [768][768]^T  1,179,648 (survives attn)
    float* pML   = (float*)(ws + 29491200);     // [24][30][128][2]    737,280
    float* pO    = (float*)(ws + 30228480);     // [24][30][128][64] 23,592,960
    // cvt buffers alias the pO region (dead until attn runs):
    us16*  xb    = (us16*)(ws + 30228480);      // [4096, 768]   6,291,456
    us16*  peb   = (us16*)(ws + 36519936);      // [2048, 768]   3,145,728
    us16*  Wqkvb = (us16*)(ws + 39665664);      // [2304][768]^T 3,538,944
    us16*  Wposb = (us16*)(ws + 43204608);      // [768][768]^T  1,179,648

    dim3 blk(256);
    cvt_all<<<1744, blk, 0, stream>>>(x, xb, 4096 * 768 / 4, pe, peb, 2048 * 768 / 4,
                                      W_qkv, Wqkvb, W_pos, Wposb, W_out, Woutb);
    gemm_dual<<<672, blk, 0, stream>>>(xb, Wqkvb, qkvb, peb, Wposb, posb);
    attn_mfma<<<dim3(30, 24), dim3(512), 0, stream>>>(qkvb, posb, u_bias, v_bias, ctxb, pO, pML);
    attn_combine<<<dim3(12, 24), blk, 0, stream>>>(pO, pML, ctxb);
    gemm_out<<<dim3(768 / 128, 4096 / 64), blk, 0, stream>>>(ctxb, Woutb, out);
}